// Round 4
// baseline (1688.929 us; speedup 1.0000x reference)
//
#include <hip/hip_runtime.h>
#include <cmath>

#define VOCAB 20000
#define EMB 300
#define FEAT 2052
#define HID 1024
#define OUTN 3000
#define NK 8
#define NS 10
#define KOBJ 36
#define BATCH 256
#define QLEN_ 14

typedef __attribute__((ext_vector_type(8))) short bf8v;
typedef __attribute__((ext_vector_type(4))) float f4v;

__device__ __forceinline__ short f2bf(float f) {
    union { float f; unsigned u; } v; v.f = f;
    unsigned r = v.u + 0x7fff + ((v.u >> 16) & 1);   // RTNE
    return (short)(r >> 16);
}
__device__ __forceinline__ float bf2f(short h) {
    union { unsigned u; float f; } v; v.u = ((unsigned)(unsigned short)h) << 16;
    return v.f;
}

// async global->LDS, 16B per lane, dest = ldsbase + lane*16 (wave-uniform base)
__device__ __forceinline__ void gload16(const short* g, short* l) {
    typedef __attribute__((address_space(1))) void gv;
    typedef __attribute__((address_space(3))) void lv;
    __builtin_amdgcn_global_load_lds((gv*)g, (lv*)l, 16, 0, 0);
}

template<int N> __device__ __forceinline__ void vmw() {
    asm volatile("s_waitcnt vmcnt(%0)" :: "n"(N) : "memory");
}
// wait so that only nf tiles (PW loads each, this wave) remain in flight
template<int PW> __device__ __forceinline__ void vmwait(int nf) {
    switch (nf) {
        case 0:  vmw<0>();      break;
        case 1:  vmw<1 * PW>(); break;
        case 2:  vmw<2 * PW>(); break;
        default: vmw<3 * PW>(); break;
    }
}

// ---------------- MFMA GEMM (bf16-in, D-deep pipelined staging, 8 waves) ----------------
// C[M,N] = A(M,K) @ B^T, A/B pre-converted bf16 (hi[,lo]) with K%32==0, rows padded.
// PREC=3: bf16x3 split (hi*hi + lo*hi + hi*lo). BM = MI*32, BN = NJ*32.
// 512 threads = 8 waves; wave grid 4(row) x 2(col); per-wave output (MI/2)*16 x NJ*16.
// NJ=8 (BN=256) raises arithmetic intensity: staged bytes/output-elem drop 2.0 -> 1.5
// for PREC3 (the L3->L2 fill path at ~6.6 TB/s is the binding constraint for big GEMMs).
// D = pipeline depth (LDS buffers); counted vmcnt keeps D-1 tiles in flight across barriers.
// Second-descriptor batching: blocks with by >= gridDim.y/2 (when A2h != null) use the
// alternate {A,B,C,bias} set -> two independent GEMMs (or K-split halves) in ONE dispatch.
// epilogue: v = acc (+C if beta) (+bias) ; relu ; *mul ; write fp32 C and/or bf16 Cb.
template<int PREC, int MI, int D, int NJ>
__global__ __launch_bounds__(512)
void mgemm_k(const short* __restrict__ Ah_g, const short* __restrict__ Al_g, int lda,
             const short* __restrict__ Bh_g, const short* __restrict__ Bl_g, int ldb,
             float* __restrict__ Cf_g, int ldc,
             short* __restrict__ Cb_g, int ldcb,
             const float* __restrict__ bias_g,
             const float* __restrict__ mul_g, int ldmul,
             int Nvalid, int K, int beta, int relu,
             const short* __restrict__ A2h, const short* __restrict__ A2l,
             const short* __restrict__ B2h, const short* __restrict__ B2l,
             float* __restrict__ C2f, short* __restrict__ C2b,
             const float* __restrict__ bias2)
{
    constexpr int BM  = MI * 32;
    constexpr int BN  = NJ * 32;
    constexpr int MIW = MI / 2;           // fragment rows per wave
    constexpr int ASZ = BM * 32;          // shorts per A tile
    constexpr int BSZ = BN * 32;          // shorts per B tile
    constexpr int NBUF = (PREC == 3) ? 2 * D : D;   // hi buffers [0,D), lo buffers [D,2D)
    __shared__ short SA[NBUF * ASZ];
    __shared__ short SB[NBUF * BSZ];

    // XCD-aware rank swizzle (R2-proven): XCD (flat%8) gets a contiguous rank range
    // in by-major order, so the ~8 column-blocks of one A-strip co-run on one XCD
    // and share the strip via its L2.
    int gx = gridDim.x, gy = gridDim.y;
    int flat = blockIdx.y * gx + blockIdx.x;
    int total = gx * gy;
    int bx, by;
    if ((total & 7) == 0) {
        int r = (flat & 7) * (total >> 3) + (flat >> 3);
        by = r / gx; bx = r - by * gx;
    } else { bx = blockIdx.x; by = blockIdx.y; }

    // second-descriptor selection (wave-uniform)
    const short *pAh = Ah_g, *pAl = Al_g, *pBh = Bh_g, *pBl = Bl_g;
    float* pCf = Cf_g; short* pCb = Cb_g;
    const float* pbias = bias_g; const float* pmul = mul_g;
    int pbeta = beta;
    if (A2h) {
        int yh = gy >> 1;
        if (by >= yh) {
            by -= yh;
            pAh = A2h; pAl = A2l; pBh = B2h; pBl = B2l;
            pCf = C2f; pCb = C2b; pbias = bias2; pmul = nullptr; pbeta = 0;
        }
    }

    int tid = threadIdx.x;
    int lane = tid & 63, wid = tid >> 6;   // 8 waves
    int m0 = by * BM, n0 = bx * BN;
    const short* Ab  = pAh + (size_t)m0 * lda;
    const short* Bb  = pBh + (size_t)n0 * ldb;
    const short* Abl = (PREC == 3) ? pAl + (size_t)m0 * lda : nullptr;
    const short* Bbl = (PREC == 3) ? pBl + (size_t)n0 * ldb : nullptr;

    constexpr int AISS = BM / 16;                         // 16-row issues per A tile
    constexpr int BISS = BN / 16;                         // 16-row issues per B tile
    constexpr int NISS = (PREC == 3) ? 2 * (AISS + BISS) : (AISS + BISS);
    constexpr int REM  = NISS & 7;                        // waves wid<REM issue PWH, else PWL
    constexpr int PWH  = (NISS + 7) >> 3;
    constexpr int PWL  = NISS >> 3;
    int rr = lane & 15;            // row within 16-row group
    int cc = (lane >> 4) * 8;      // k-offset (8 bf16 = 16B)

    // stage tile (k0 shorts into K) into buffer q
    auto stage = [&](int q, int k0) {
        short* sa  = SA + q * ASZ;
        short* sb  = SB + q * BSZ;
        short* sal = SA + (D + q) * ASZ;
        short* sbl = SB + (D + q) * BSZ;
        #pragma unroll
        for (int t = wid; t < NISS; t += 8) {
            int u = t;
            const short* g; short* l;
            if (u < AISS)               {                     g = Ab  + (size_t)(u*16+rr)*lda + k0 + cc; l = sa  + u*512; }
            else if (u < AISS + BISS)   { u -= AISS;          g = Bb  + (size_t)(u*16+rr)*ldb + k0 + cc; l = sb  + u*512; }
            else if (u < 2*AISS + BISS) { u -= AISS + BISS;   g = Abl + (size_t)(u*16+rr)*lda + k0 + cc; l = sal + u*512; }
            else                        { u -= 2*AISS + BISS; g = Bbl + (size_t)(u*16+rr)*ldb + k0 + cc; l = sbl + u*512; }
            gload16(g, l);
        }
    };

    f4v acc[MIW][NJ] = {};
    int nk = K >> 5;                       // K/32 tiles
    int P = (D - 1 < nk) ? (D - 1) : nk;   // prologue depth
    for (int q = 0; q < P; ++q) stage(q, q << 5);

    for (int kt = 0; kt < nk; ++kt) {
        int nxt = kt + D - 1;
        if (nxt < nk) stage(nxt % D, nxt << 5);
        // tiles in flight beyond kt (per wave); wait so tile kt is landed
        int rem = nk - 1 - kt;
        int nf = rem < D - 1 ? rem : D - 1;
        if (REM == 0 || wid < REM) vmwait<PWH>(nf); else vmwait<PWL>(nf);
        __builtin_amdgcn_s_barrier();
        __builtin_amdgcn_sched_barrier(0);
        {
            int q = kt % D;
            int wy = wid >> 1, wx = wid & 1;
            int quad = lane >> 4, l15 = lane & 15;
            const bf8v* A8 = (const bf8v*)(SA + q * ASZ);
            const bf8v* B8 = (const bf8v*)(SB + q * BSZ);
            bf8v ah[MIW], bh[NJ];
            #pragma unroll
            for (int i = 0; i < MIW; i++) ah[i] = A8[(wy*MIW + i)*64 + quad*16 + l15];
            #pragma unroll
            for (int j = 0; j < NJ; j++)  bh[j] = B8[(wx*NJ + j)*64 + quad*16 + l15];
            if (PREC == 3) {
                const bf8v* A8l = (const bf8v*)(SA + (D + q) * ASZ);
                const bf8v* B8l = (const bf8v*)(SB + (D + q) * BSZ);
                bf8v al[MIW], bl[NJ];
                #pragma unroll
                for (int i = 0; i < MIW; i++) al[i] = A8l[(wy*MIW + i)*64 + quad*16 + l15];
                #pragma unroll
                for (int j = 0; j < NJ; j++)  bl[j] = B8l[(wx*NJ + j)*64 + quad*16 + l15];
                #pragma unroll
                for (int i = 0; i < MIW; i++)
                    #pragma unroll
                    for (int j = 0; j < NJ; j++) {
                        acc[i][j] = __builtin_amdgcn_mfma_f32_16x16x32_bf16(ah[i], bh[j], acc[i][j], 0, 0, 0);
                        acc[i][j] = __builtin_amdgcn_mfma_f32_16x16x32_bf16(al[i], bh[j], acc[i][j], 0, 0, 0);
                        acc[i][j] = __builtin_amdgcn_mfma_f32_16x16x32_bf16(ah[i], bl[j], acc[i][j], 0, 0, 0);
                    }
            } else {
                #pragma unroll
                for (int i = 0; i < MIW; i++)
                    #pragma unroll
                    for (int j = 0; j < NJ; j++)
                        acc[i][j] = __builtin_amdgcn_mfma_f32_16x16x32_bf16(ah[i], bh[j], acc[i][j], 0, 0, 0);
            }
        }
        __builtin_amdgcn_sched_barrier(0);
        __builtin_amdgcn_s_barrier();      // protect buf (kt % D) before next-iter stage overwrites it
        __builtin_amdgcn_sched_barrier(0);
    }

    // epilogue (C/D: col = lane&15, row = quad*4 + reg)
    int wy = wid >> 1, wx = wid & 1;
    int quad = lane >> 4, l15 = lane & 15;
    #pragma unroll
    for (int i = 0; i < MIW; i++) {
        int mb = m0 + wy * (MIW * 16) + i * 16 + quad * 4;
        #pragma unroll
        for (int j = 0; j < NJ; j++) {
            int n = n0 + wx * (NJ * 16) + j * 16 + l15;
            bool nin = n < Nvalid;
            #pragma unroll
            for (int r = 0; r < 4; r++) {
                int m = mb + r;
                float v = acc[i][j][r];
                if (nin) {
                    if (pbeta) v += pCf[(size_t)m * ldc + n];
                    if (pbias) v += pbias[n];
                    if (relu)  v = fmaxf(v, 0.f);
                    if (pmul)  v *= pmul[(size_t)m * ldmul + n];
                    if (pCf) pCf[(size_t)m * ldc + n] = v;
                    if (pCb) pCb[(size_t)m * ldcb + n] = f2bf(v);
                } else if (pCb && n < ldcb) {
                    pCb[(size_t)m * ldcb + n] = 0;   // zero-fill K-pad cols of bf16 outputs
                }
            }
        }
    }
}

static void mgx(hipStream_t s, int prec, int mi, int nj,
                const short* Ah, const short* Al, int lda,
                const short* Bh, const short* Bl, int ldb,
                float* Cf, int ldc, short* Cb, int ldcb,
                const float* bias, const float* mul, int ldmul,
                int M, int N, int K, int beta, int relu,
                int ydup,
                const short* A2h, const short* A2l,
                const short* B2h, const short* B2l,
                float* C2f, short* C2b, const float* bias2)
{
    int bn = nj * 32;
    dim3 grid((N + bn - 1) / bn, (M / (mi * 32)) * ydup);
    #define ARGS Ah,Al,lda,Bh,Bl,ldb,Cf,ldc,Cb,ldcb,bias,mul,ldmul,N,K,beta,relu,A2h,A2l,B2h,B2l,C2f,C2b,bias2
    if (prec == 3) {
        if      (mi == 4 && nj == 8) mgemm_k<3,4,2,8><<<grid,512,0,s>>>(ARGS);  // 96 KB LDS
        else if (mi == 4)            mgemm_k<3,4,2,4><<<grid,512,0,s>>>(ARGS);  // 64 KB
        else                         mgemm_k<3,2,3,4><<<grid,512,0,s>>>(ARGS);  // 72 KB, D=3
    } else {
        if (mi == 4)                 mgemm_k<1,4,4,4><<<grid,512,0,s>>>(ARGS);  // 48 KB
        else                         mgemm_k<1,2,4,4><<<grid,512,0,s>>>(ARGS);  // 40 KB
    }
    #undef ARGS
}

static void mg(hipStream_t s, int prec, int mi,
               const short* Ah, const short* Al, int lda,
               const short* Bh, const short* Bl, int ldb,
               float* Cf, int ldc, short* Cb, int ldcb,
               const float* bias, const float* mul, int ldmul,
               int M, int N, int K, int beta, int relu)
{
    mgx(s, prec, mi, 4, Ah, Al, lda, Bh, Bl, ldb, Cf, ldc, Cb, ldcb, bias, mul, ldmul,
        M, N, K, beta, relu, 1, nullptr, nullptr, nullptr, nullptr, nullptr, nullptr, nullptr);
}

// ---------------- conversion / small kernels ----------------
__global__ void fill0_k(float* p, int n) {
    int i = blockIdx.x * 256 + threadIdx.x;
    if (i < n) p[i] = 0.f;
}

// fp32 (srows,scols,sld) -> bf16 hi[,lo] (.., dld) zero-padded
__global__ void cvt_k(const float* __restrict__ src, int sld, int srows, int scols,
                      short* __restrict__ hi, short* __restrict__ lo, int dld, int n) {
    int i = blockIdx.x * 256 + threadIdx.x;
    if (i >= n) return;
    int r = i / dld, c = i - r * dld;
    float v = (r < srows && c < scols) ? src[(size_t)r * sld + c] : 0.f;
    short h = f2bf(v);
    hi[i] = h;
    if (lo) lo[i] = f2bf(v - bf2f(h));
}

__global__ void embed_k(const int* __restrict__ q, const float* __restrict__ wemb,
                        short* __restrict__ hi, short* __restrict__ lo) {
    int i = blockIdx.x * 256 + threadIdx.x;
    if (i >= BATCH * QLEN_ * 320) return;
    int c = i % 320; int bt = i / 320;
    float v = (c < EMB) ? wemb[(size_t)q[bt] * EMB + c] : 0.f;
    short h = f2bf(v);
    hi[i] = h;
    lo[i] = f2bf(v - bf2f(h));
}

// GRU pointwise; gh is split-K: gates = gi + gh + gh2
__global__ void gru_point_k(const float* __restrict__ gi, int ldgi, const float* __restrict__ gh,
                            const float* __restrict__ gh2,
                            const int* __restrict__ qlen, float* __restrict__ h,
                            short* __restrict__ qh, short* __restrict__ ql, int t) {
    int i = blockIdx.x * 256 + threadIdx.x;
    if (i >= BATCH * HID) return;
    int b = i / HID; int j = i % HID;
    float ir = gi[(size_t)b * ldgi + j];
    float iz = gi[(size_t)b * ldgi + HID + j];
    float in = gi[(size_t)b * ldgi + 2 * HID + j];
    float hr = gh[(size_t)b * 3 * HID + j]          + gh2[(size_t)b * 3 * HID + j];
    float hz = gh[(size_t)b * 3 * HID + HID + j]    + gh2[(size_t)b * 3 * HID + HID + j];
    float hn = gh[(size_t)b * 3 * HID + 2 * HID + j]+ gh2[(size_t)b * 3 * HID + 2 * HID + j];
    float r = 1.f / (1.f + expf(-(ir + hr)));
    float z = 1.f / (1.f + expf(-(iz + hz)));
    float n = tanhf(in + r * hn);
    float hold = h[i];
    float val = (t < qlen[b]) ? ((1.f - z) * n + z * hold) : hold;
    h[i] = val;
    short hh = f2bf(val);
    qh[i] = hh;
    ql[i] = f2bf(val - bf2f(hh));
}

__global__ __launch_bounds__(256)
void attraw_k(const float* __restrict__ proj, const float* __restrict__ qproj,
              const float* __restrict__ attw, const float* __restrict__ attb,
              float* __restrict__ raw, int L) {
    int wave = blockIdx.x * 4 + (threadIdx.x >> 6);
    int lane = threadIdx.x & 63;
    if (wave >= BATCH * L) return;
    int b = wave / L;
    const float* p = proj + (size_t)wave * HID;
    const float* q = qproj + (size_t)b * HID;
    float s = 0.f;
    for (int hh = lane; hh < HID; hh += 64) s += p[hh] * q[hh] * attw[hh];
    #pragma unroll
    for (int o = 32; o; o >>= 1) s += __shfl_down(s, o, 64);
    if (lane == 0) raw[wave] = s + attb[0];
}

__global__ void softmax_k(float* raw, int L) {
    int b = blockIdx.x * blockDim.x + threadIdx.x;
    if (b >= BATCH) return;
    float* r = raw + (size_t)b * L;
    float mx = -1e30f;
    for (int l = 0; l < L; l++) mx = fmaxf(mx, r[l]);
    float sum = 0.f;
    for (int l = 0; l < L; l++) { float e = expf(r[l] - mx); r[l] = e; sum += e; }
    float inv = 1.f / sum;
    for (int l = 0; l < L; l++) r[l] *= inv;
}

// bf16-out weighted sum with K-pad: out[b, c<dld] = sum_l src[(b*L+l)*sF + c] * att[b*L+l]
__global__ void wsumb_k(const float* __restrict__ src, int sF, const float* __restrict__ att,
                        int L, short* __restrict__ outh, int dld, int n) {
    int i = blockIdx.x * 256 + threadIdx.x;
    if (i >= n) return;
    int c = i % dld; int b = i / dld;
    float s = 0.f;
    if (c < sF)
        for (int l = 0; l < L; l++) s += src[((size_t)b * L + l) * sF + c] * att[b * L + l];
    outh[i] = f2bf(s);
}

// jax.lax.top_k: descending, ties -> lowest index
__global__ void topk_k(const float* __restrict__ att, int* __restrict__ idx) {
    int b = blockIdx.x * blockDim.x + threadIdx.x;
    if (b >= BATCH) return;
    float v[KOBJ]; bool taken[KOBJ];
    for (int l = 0; l < KOBJ; l++) { v[l] = att[(size_t)b * KOBJ + l]; taken[l] = false; }
    for (int s = 0; s < NS; s++) {
        float best = -1e30f; int bi = 0;
        for (int l = 0; l < KOBJ; l++)
            if (!taken[l] && v[l] > best) { best = v[l]; bi = l; }
        taken[bi] = true;
        idx[b * NS + s] = bi;
    }
}

// gather top-k rows: fp32 (ld 2052) + bf16 hi (ld 2080, zero pad)
__global__ void gather_k(const float* __restrict__ img, const int* __restrict__ idx,
                         float* __restrict__ outf, short* __restrict__ outh) {
    int i = blockIdx.x * 256 + threadIdx.x;
    if (i >= BATCH * NS * 2080) return;
    int c = i % 2080; int bs = i / 2080; int b = bs / NS; int s = bs % NS;
    float v = 0.f;
    if (c < FEAT) {
        v = img[((size_t)b * KOBJ + idx[b * NS + s]) * FEAT + c];
        outf[(size_t)bs * FEAT + c] = v;
    }
    outh[i] = f2bf(v);
}

__global__ void kw_k(const float* __restrict__ image, const int* __restrict__ tidx,
                     const float* __restrict__ mu1, const float* __restrict__ sig1,
                     const float* __restrict__ mu2, const float* __restrict__ sig2,
                     float* __restrict__ kw1, float* __restrict__ kw2) {
    int i = blockIdx.x * blockDim.x + threadIdx.x;
    if (i >= BATCH * NS * NS) return;
    int m = i % NS; int bn = i / NS; int b = bn / NS; int n = bn % NS;
    const float* bbn = image + ((size_t)b * KOBJ + tidx[b * NS + n]) * FEAT + (FEAT - 4);
    const float* bbm = image + ((size_t)b * KOBJ + tidx[b * NS + m]) * FEAT + (FEAT - 4);
    float cnx = bbn[0] + 0.5f * (bbn[2] - bbn[0]);
    float cny = bbn[1] + 0.5f * (bbn[3] - bbn[1]);
    float cmx = bbm[0] + 0.5f * (bbm[2] - bbm[0]);
    float cmy = bbm[1] + 0.5f * (bbm[3] - bbm[1]);
    float d0 = cnx - cmx, d1 = cny - cmy;
    float rho = sqrtf(d0 * d0 + d1 * d1);
    float theta = atan2f(d0, d1);
    #pragma unroll
    for (int k = 0; k < NK; k++) {
        float a1 = (rho   - mu1[k * 2 + 0]) / (1e-14f + sig1[k * 2 + 0]);
        float b1 = (theta - mu1[k * 2 + 1]) / (1e-14f + sig1[k * 2 + 1]);
        kw1[(size_t)i * NK + k] = expf(-0.5f * (a1 * a1 + b1 * b1));
        float a2 = (rho   - mu2[k * 2 + 0]) / (1e-14f + sig2[k * 2 + 0]);
        float b2 = (theta - mu2[k * 2 + 1]) / (1e-14f + sig2[k * 2 + 1]);
        kw2[(size_t)i * NK + k] = expf(-0.5f * (a2 * a2 + b2 * b2));
    }
}

// graph-conv mix, kw cached in LDS, Y read exactly once.
// out[(b,n),c] = relu(bias[c] + sum_m kw[b][n][m][c/KO] * Y[(b,m),c]); bf16 (+opt fp32)
// grid: (CT/256, BATCH), 256 threads
__global__ __launch_bounds__(256)
void mixn_k(const float* __restrict__ Y, const float* __restrict__ kw,
            const float* __restrict__ bias, short* __restrict__ outh,
            float* __restrict__ outf, int KO, int CT) {
    __shared__ float kws[NS * NS * NK];   // 800
    int b = blockIdx.y;
    for (int i = threadIdx.x; i < NS * NS * NK; i += 256)
        kws[i] = kw[(size_t)b * (NS * NS * NK) + i];
    __syncthreads();
    int c = blockIdx.x * 256 + threadIdx.x;
    int k = c / KO;
    const float* Yp = Y + ((size_t)b * NS) * CT + c;
    float acc[NS];
    #pragma unroll
    for (int n = 0; n < NS; n++) acc[n] = 0.f;
    #pragma unroll
    for (int m = 0; m < NS; m++) {
        float y = Yp[(size_t)m * CT];
        #pragma unroll
        for (int n = 0; n < NS; n++) acc[n] += kws[n * (NS * NK) + m * NK + k] * y;
    }
    float bc = bias[c];
    #pragma unroll
    for (int n = 0; n < NS; n++) {
        float s = fmaxf(acc[n] + bc, 0.f);
        size_t o = ((size_t)b * NS + n) * CT + c;
        outh[o] = f2bf(s);
        if (outf) outf[o] = s;
    }
}

// out[i] = t1[i] + t2[i]  (biases already applied in GEMM halves)
__global__ void addout_k(const float* __restrict__ t1, const float* __restrict__ t2,
                         float* __restrict__ out, int n) {
    int i = blockIdx.x * 256 + threadIdx.x;
    if (i < n) out[i] = t1[i] + t2[i];
}

// transpose+convert per k-slice: dst[k*O+o][f<dld] = src[k][f][o] (zero-pad f>=S)
__global__ void packcvt_k(const float* __restrict__ src, short* __restrict__ dst,
                          int S, int O, int dld) {
    __shared__ float t[32][33];
    int k = blockIdx.z;
    const float* s = src + (size_t)k * S * O;
    short* d = dst + (size_t)k * O * dld;
    int f0 = blockIdx.y * 32, o0 = blockIdx.x * 32;
    for (int i = threadIdx.y; i < 32; i += 8) {
        int f = f0 + i, o = o0 + threadIdx.x;
        t[i][threadIdx.x] = (f < S && o < O) ? s[(size_t)f * O + o] : 0.f;
    }
    __syncthreads();
    for (int i = threadIdx.y; i < 32; i += 8) {
        int o = o0 + i, f = f0 + threadIdx.x;
        if (o < O && f < dld) d[(size_t)o * dld + f] = f2bf(t[threadIdx.x][i]);
    }
}

// ---------------- launch ----------------
extern "C" void kernel_launch(void* const* d_in, const int* in_sizes, int n_in,
                              void* d_out, int out_size, void* d_ws, size_t ws_size,
                              hipStream_t stream)
{
    const int*   question  = (const int*)d_in[0];
    const float* image     = (const float*)d_in[1];
    const int*   qlen      = (const int*)d_in[3];
    const float* wembed    = (const float*)d_in[4];
    const float* gru_wih   = (const float*)d_in[5];
    const float* gru_whh   = (const float*)d_in[6];
    const float* gru_bih   = (const float*)d_in[7];
    const float* gru_bhh   = (const float*)d_in[8];
    const float* ia_img_w  = (const float*)d_in[9];
    const float* ia_img_b  = (const float*)d_in[10];
    const float* ia_txt_w  = (const float*)d_in[11];
    const float* ia_txt_b  = (const float*)d_in[12];
    const float* ia_att_w  = (const float*)d_in[13];
    const float* ia_att_b  = (const float*)d_in[14];
    const float* ga_img_w  = (const float*)d_in[15];
    const float* ga_img_b  = (const float*)d_in[16];
    const float* ga_txt_w  = (const float*)d_in[17];
    const float* ga_txt_b  = (const float*)d_in[18];
    const float* ga_att_w  = (const float*)d_in[19];
    const float* ga_att_b  = (const float*)d_in[20];
    const float* gc1_mu    = (const float*)d_in[21];
    const float* gc1_sigma = (const float*)d_in[22];
    const float* gc1_w     = (const float*)d_in[23];
    const float* gc1_b     = (const float*)d_in[24];
    const float* gc2_mu    = (const float*)d_in[25];
    const float* gc2_sigma = (const float*)d_in[26];
    const float* gc2_w     = (const float*)d_in[27];
    const float* gc2_b     = (const float*)d_in[28];
    const float* out1_w    = (const float*)d_in[29];
    const float* out1_b    = (const float*)d_in[30];
    const float* out2_w    = (const float*)d_in[31];
    const float* out2_b    = (const float*)d_in[32];
    const float* iout1_w   = (const float*)d_in[33];
    const float* iout1_b   = (const float*)d_in[34];
    const float* iout2_w   = (const float*)d_in[35];
    const float* iout2_b   = (const float*)d_in[36];
    float* out = (float*)d_out;

    float* ws = (float*)d_ws;
    size_t off = 0;
    auto alloc  = [&](size_t n)   { size_t o = off; off += (n + 63) & ~(size_t)63; return ws + o; };
    auto allocS = [&](size_t nsh) { return (short*)alloc((nsh + 1) >> 1); };

    // persistent fp32
    float* qenc   = alloc((size_t)BATCH * HID);
    float* att_ia = alloc((size_t)BATCH * KOBJ);
    float* att_ga = alloc((size_t)BATCH * NS);
    int*   tidx   = (int*)alloc((size_t)BATCH * NS);
    float* timg_f = alloc((size_t)2560 * FEAT);
    float* kw1    = alloc((size_t)BATCH * NS * NS * NK);
    float* kw2    = alloc((size_t)BATCH * NS * NS * NK);
    // persistent bf16 (hi/lo pairs for PREC3 scoring path)
    short* wih_h   = allocS((size_t)3072 * 320);  short* wih_l   = allocS((size_t)3072 * 320);
    short* whh_h   = allocS((size_t)3072 * 1024); short* whh_l   = allocS((size_t)3072 * 1024);
    short* iaimg_h = allocS((size_t)1024 * 2080); short* iaimg_l = allocS((size_t)1024 * 2080);
    short* iatxt_h = allocS((size_t)1024 * 1024); short* iatxt_l = allocS((size_t)1024 * 1024);
    short* emb_h   = allocS((size_t)3584 * 320);  short* emb_l   = allocS((size_t)3584 * 320);
    short* qenc_h  = allocS((size_t)256 * 1024);  short* qenc_l  = allocS((size_t)256 * 1024);
    // phase-reused regions
    float* R1 = alloc(12600000);   // 25.2M shorts
    float* U  = alloc(19200000);   // 38.4M shorts

    // --- phase-local views ---
    // A: GRU
    float* gi_all = R1;                          // 3584 x 3072
    float* gh     = R1 + 11010048;               // 256 x 3072
    float* gh2    = R1 + 11796480;               // 256 x 3072 (split-K second half)
    // B: image attention
    float* improj = R1;                          // 9216 x 1024
    float* qproj  = R1 + 9437184;                // 256 x 1024
    short* img_h  = (short*)U;                   // 9216 x 2080
    short* img_l  = (short*)U + 19169280;
    short* imatt_h = (short*)U + 13189120;       // 256 x 2080 (after img dead)
    // C: graph convs
    float* Y1 = R1;                              // 2560 x 2048
    float* Y2 = R1 + 5242880;                    // 2560 x 1024
    short* gc1t_h = (short*)(R1 + 7864320);      // 2048 x 2080
    short* gc2t_h = (short*)(R1 + 7864320) + 4259840; // 1024 x 2048
    short* timg_h = (short*)U;                   // 2560 x 2080
    short* h1_h   = (short*)U + 5324800;         // 2560 x 2048
    short* h2_h   = (short*)U + 10567680;        // 2560 x 1024
    float* h2_f   = (float*)((short*)U + 20807680); // 2560 x 1024 fp32
    // D: graph attention
    float* gproj   = R1;                         // 2560 x 1024
    float* qproj2  = R1 + 2621440;               // 256 x 1024
    float* gtmp    = R1 + 2883584;               // 256 x 1024
    short* gatt_img_h = (short*)U + 13721600;    // 256 x 2080
    short* gatt_h2_h  = (short*)U + 14254080;    // 256 x 1024
    short* gcomb_h = (short*)U + 14516224;       // 256 x 1024
    short* icomb_h = (short*)U + 14778368;       // 256 x 1024 (adjacent to gcomb)
    short* hid1_h  = (short*)U + 15040512;       // 256 x 3008
    short* hid2_h  = (short*)U + 15810560;       // 256 x 3008 (adjacent to hid1)
    short* gaw_img_h = (short*)U + 16580608;     // 1024 x 2080
    short* gaw_h2_h  = (short*)U + 18710528;     // 1024 x 1024
    short* gatxt_h   = (short*)U + 19759104;     // 1024 x 1024
    float* tmp1 = (float*)((short*)U + 26050560); // 256 x 3000 fp32
    float* tmp2 = tmp1 + 768000;                  // 256 x 3000 fp32
    // E: output weights (into R1, after gcomb done)
    short* o1w_h  = (short*)R1;                  // 3072 x 1024
    short* io1w_h = (short*)R1 + 3145728;
    short* o2w_h  = (short*)R1 + 6291456;        // 3072 x 3008
    short* io2w_h = (short*)R1 + 15532032;

    auto NB = [](size_t n) { return (unsigned)((n + 255) / 256); };

    // ===== conversions (phase A/B weights + image) =====
    cvt_k<<<NB(983040),  256, 0, stream>>>(gru_wih, 300, 3072, 300, wih_h, wih_l, 320, 983040);
    cvt_k<<<NB(3145728), 256, 0, stream>>>(gru_whh, 1024, 3072, 1024, whh_h, whh_l, 1024, 3145728);
    cvt_k<<<NB(2129920), 256, 0, stream>>>(ia_img_w, FEAT, 1024, FEAT, iaimg_h, iaimg_l, 2080, 2129920);
    cvt_k<<<NB(1048576), 256, 0, stream>>>(ia_txt_w, 1024, 1024, 1024, iatxt_h, iatxt_l, 1024, 1048576);
    cvt_k<<<NB(19169280),256, 0, stream>>>(image, FEAT, 9216, FEAT, img_h, img_l, 2080, 19169280);
    embed_k<<<NB(1146880), 256, 0, stream>>>(question, wembed, emb_h, emb_l);
    fill0_k<<<NB(262144), 256, 0, stream>>>(qenc, 262144);
    fill0_k<<<NB(262144), 256, 0, stream>>>((float*)qenc_h, 262144);   // zeros qenc_h + qenc_l

    // ===== Phase A: GRU =====
    mg(stream, 3, 4, emb_h, emb_l, 320, wih_h, wih_l, 320, gi_all, 3072, nullptr, 0,
       gru_bih, nullptr, 0, 3584, 3072, 320, 0, 0);
    for (int t = 0; t < QLEN_; t++) {
        // split-K=2 in one dispatch: half0 -> gh (with bias), half1 (K offset 512) -> gh2
        mgx(stream, 3, 2, 4, qenc_h, qenc_l, 1024, whh_h, whh_l, 1024, gh, 3072, nullptr, 0,
            gru_bhh, nullptr, 0, 256, 3072, 512, 0, 0,
            2, qenc_h + 512, qenc_l + 512, whh_h + 512, whh_l + 512, gh2, nullptr, nullptr);
        gru_point_k<<<NB(262144), 256, 0, stream>>>(gi_all + (size_t)t * 3 * HID, QLEN_ * 3 * HID,
                                                    gh, gh2, qlen, qenc, qenc_h, qenc_l, t);
    }

    // ===== Phase B: image attention (scoring = PREC3; BN=256 high-intensity tile) =====
    mgx(stream, 3, 4, 8, img_h, img_l, 2080, iaimg_h, iaimg_l, 2080, improj, 1024, nullptr, 0,
        ia_img_b, nullptr, 0, 9216, 1024, 2080, 0, 1,
        1, nullptr, nullptr, nullptr, nullptr, nullptr, nullptr, nullptr);
    mg(stream, 3, 2, qenc_h, qenc_l, 1024, iatxt_h, iatxt_l, 1024, qproj, 1024, nullptr, 0,
       ia_txt_b, nullptr, 0, 256, 1024, 1024, 0, 1);
    attraw_k<<<(BATCH * KOBJ) / 4, 256, 0, stream>>>(improj, qproj, ia_att_w, ia_att_b, att_ia, KOBJ);
    softmax_k<<<1, 256, 0, stream>>>(att_ia, KOBJ);
    wsumb_k<<<NB(532480), 256, 0, stream>>>(image, FEAT, att_ia, KOBJ, imatt_h, 2080, 532480);
    mg(stream, 1, 2, imatt_h, nullptr, 2080, iaimg_h, nullptr, 2080, nullptr, 0, icomb_h, 1024,
       ia_img_b, qproj, 1024, 256, 1024, 2080, 0, 1);

    // ===== Phase C: top-k + graph convs =====
    topk_k<<<1, 256, 0, stream>>>(att_ia, tidx);
    gather_k<<<NB(5324800), 256, 0, stream>>>(image, tidx, timg_f, timg_h);
    kw_k<<<NB(25600), 256, 0, stream>>>(image, tidx, gc1_mu, gc1_sigma, gc2_mu, gc2_sigma, kw1, kw2);
    packcvt_k<<<dim3(8, 65, NK), dim3(32, 8), 0, stream>>>(gc1_w, gc1t_h, FEAT, 256, 2080);
    packcvt_k<<<dim3(4, 64, NK), dim3(32, 8), 0, stream>>>(gc2_w, gc2t_h, 2048, 128, 2048);
    mg(stream, 1, 4, timg_h, nullptr, 2080, gc1t_h, nullptr, 2080, Y1, 2048, nullptr, 0,
       nullptr, nullptr, 0, 2560, 2048, 2080, 0, 0);
    mixn_k<<<dim3(8, BATCH), 256, 0, stream>>>(Y1, kw1, gc1_b, h1_h, nullptr, 256, 2048);
    mg(stream, 1, 4, h1_h, nullptr, 2048, gc2t_h, nullptr, 2048, Y2, 1024, nullptr, 0,
       nullptr, nullptr, 0, 2560, 1024, 2048, 0, 0);
    mixn_k<<<dim3(4, BATCH), 256, 0, stream>>>(Y2, kw2, gc2_b, h2_h, h2_f, 128, 1024);

    // ===== Phase D: graph attention ([timg | h2], never materialized) =====
    cvt_k<<<NB(2129920), 256, 0, stream>>>(ga_img_w, FEAT + HID, 1024, FEAT, gaw_img_h, nullptr, 2080, 2129920);
    cvt_k<<<NB(1048576), 256, 0, stream>>>(ga_img_w + FEAT, FEAT + HID, 1024, HID, gaw_h2_h, nullptr, 1024, 1048576);
    cvt_k<<<NB(1048576), 256, 0, stream>>>(ga_txt_w, 1024, 1024, 1024, gatxt_h, nullptr, 1024, 1048576);
    mg(stream, 1, 4, timg_h, nullptr, 2080, gaw_img_h, nullptr, 2080, gproj, 1024, nullptr, 0,
       nullptr, nullptr, 0, 2560, 1024, 2080, 0, 0);
    mg(stream, 1, 4, h2_h, nullptr, 1024, gaw_h2_h, nullptr, 1024, gproj, 1024, nullptr, 0,
       ga_img_b, nullptr, 0, 2560, 1024, 1024, 1, 1);
    mg(stream, 1, 2, qenc_h, nullptr, 1024, gatxt_h, nullptr, 1024, qproj2, 1024, nullptr, 0,
       ga_txt_b, nullptr, 0, 256, 1024, 1024, 0, 1);
    attraw_k<<<(BATCH * NS) / 4, 256, 0, stream>>>(gproj, qproj2, ga_att_w, ga_att_b, att_ga, NS);
    softmax_k<<<1, 256, 0, stream>>>(att_ga, NS);
    wsumb_k<<<NB(532480), 256, 0, stream>>>(timg_f, FEAT, att_ga, NS, gatt_img_h, 2080, 532480);
    wsumb_k<<<NB(262144), 256, 0, stream>>>(h2_f, HID, att_ga, NS, gatt_h2_h, 1024, 262144);
    mg(stream, 1, 2, gatt_img_h, nullptr, 2080, gaw_img_h, nullptr, 2080, gtmp, 1024, nullptr, 0,
       nullptr, nullptr, 0, 256, 1024, 2080, 0, 0);
    mg(stream, 1, 2, gatt_h2_h, nullptr, 1024, gaw_h2_h, nullptr, 1024, gtmp, 1024, gcomb_h, 1024,
       ga_img_b, qproj2, 1024, 256, 1024, 1024, 1, 1);

    // ===== Phase E: output MLPs (pairs merged into single dispatches) =====
    cvt_k<<<NB(3145728), 256, 0, stream>>>(out1_w, 1024, OUTN, 1024, o1w_h, nullptr, 1024, 3145728);
    cvt_k<<<NB(3145728), 256, 0, stream>>>(iout1_w, 1024, OUTN, 1024, io1w_h, nullptr, 1024, 3145728);
    cvt_k<<<NB(9240576), 256, 0, stream>>>(out2_w, OUTN, OUTN, OUTN, o2w_h, nullptr, 3008, 9240576);
    cvt_k<<<NB(9240576), 256, 0, stream>>>(iout2_w, OUTN, OUTN, OUTN, io2w_h, nullptr, 3008, 9240576);
    // hid1 = relu(gcomb@o1w^T + b) ; hid2 = relu(icomb@io1w^T + b)  -- one dispatch
    mgx(stream, 1, 2, 4, gcomb_h, nullptr, 1024, o1w_h, nullptr, 1024, nullptr, 0, hid1_h, 3008,
        out1_b, nullptr, 0, 256, OUTN, 1024, 0, 1,
        2, icomb_h, nullptr, io1w_h, nullptr, nullptr, hid2_h, iout1_b);
    // tmp1 = hid1@o2w^T + b2 ; tmp2 = hid2@io2w^T + ib2  -- one dispatch, then sum
    mgx(stream, 1, 2, 4, hid1_h, nullptr, 3008, o2w_h, nullptr, 3008, tmp1, 3000, nullptr, 0,
        out2_b, nullptr, 0, 256, OUTN, 3008, 0, 0,
        2, hid2_h, nullptr, io2w_h, nullptr, tmp2, nullptr, iout2_b);
    addout_k<<<NB(768000), 256, 0, stream>>>(tmp1, tmp2, out, 768000);
}

// Round 5
// 1555.929 us; speedup vs baseline: 1.0855x; 1.0855x over previous
//
#include <hip/hip_runtime.h>
#include <cmath>

#define VOCAB 20000
#define EMB 300
#define FEAT 2052
#define HID 1024
#define OUTN 3000
#define NK 8
#define NS 10
#define KOBJ 36
#define BATCH 256
#define QLEN_ 14

typedef __attribute__((ext_vector_type(8))) short bf8v;
typedef __attribute__((ext_vector_type(4))) float f4v;

__device__ __forceinline__ short f2bf(float f) {
    union { float f; unsigned u; } v; v.f = f;
    unsigned r = v.u + 0x7fff + ((v.u >> 16) & 1);   // RTNE
    return (short)(r >> 16);
}
__device__ __forceinline__ float bf2f(short h) {
    union { unsigned u; float f; } v; v.u = ((unsigned)(unsigned short)h) << 16;
    return v.f;
}

// async global->LDS, 16B per lane, dest = ldsbase + lane*16 (wave-uniform base)
__device__ __forceinline__ void gload16(const short* g, short* l) {
    typedef __attribute__((address_space(1))) void gv;
    typedef __attribute__((address_space(3))) void lv;
    __builtin_amdgcn_global_load_lds((gv*)g, (lv*)l, 16, 0, 0);
}

template<int N> __device__ __forceinline__ void vmw() {
    asm volatile("s_waitcnt vmcnt(%0)" :: "n"(N) : "memory");
}
// wait so that only nf tiles (PW loads each, this wave) remain in flight
template<int PW> __device__ __forceinline__ void vmwait(int nf) {
    switch (nf) {
        case 0:  vmw<0>();      break;
        case 1:  vmw<1 * PW>(); break;
        case 2:  vmw<2 * PW>(); break;
        default: vmw<3 * PW>(); break;
    }
}

// XCD-aware rank swizzle (R2-proven): XCD (flat%8) gets a contiguous rank range in
// by-major order -> column-blocks of one A-strip co-run on one XCD and k-lockstep.
__device__ __forceinline__ void xcd_swz(int& bx, int& by) {
    int gx = gridDim.x, gy = gridDim.y;
    int flat = blockIdx.y * gx + blockIdx.x;
    int total = gx * gy;
    if ((total & 7) == 0) {
        int r = (flat & 7) * (total >> 3) + (flat >> 3);
        by = r / gx; bx = r - by * gx;
    } else { bx = blockIdx.x; by = blockIdx.y; }
}

// ---------------- MFMA GEMM (bf16-in, D-deep pipelined staging, 8 waves) ----------------
// C[M,N] = A(M,K) @ B^T, A/B pre-converted bf16 (hi[,lo]) with K%32==0, rows padded.
// PREC=3: bf16x3 split (hi*hi + lo*hi + hi*lo). BM = MI*32, BN = 128.
// 512 threads = 8 waves; wave grid 4(row) x 2(col); per-wave output (MI/2)*16 x 64.
// KEEP LDS <= 64KB so >=2 blocks/CU co-reside: with the per-K-step barrier, a lone
// block stalls its whole CU on straggler loads; a co-resident block's MFMA covers it
// (R2/R3/R4 evidence: 64KB/2blk = 186us; 96KB/1blk = 284-310us regardless of FETCH).
// Second-descriptor batching: blocks with by >= gridDim.y/2 (when A2h != null) use the
// alternate {A,B,C,bias} set -> two independent GEMMs (or K-split halves) in ONE dispatch.
template<int PREC, int MI, int D>
__global__ __launch_bounds__(512)
void mgemm_k(const short* __restrict__ Ah_g, const short* __restrict__ Al_g, int lda,
             const short* __restrict__ Bh_g, const short* __restrict__ Bl_g, int ldb,
             float* __restrict__ Cf_g, int ldc,
             short* __restrict__ Cb_g, int ldcb,
             const float* __restrict__ bias_g,
             const float* __restrict__ mul_g, int ldmul,
             int Nvalid, int K, int beta, int relu,
             const short* __restrict__ A2h, const short* __restrict__ A2l,
             const short* __restrict__ B2h, const short* __restrict__ B2l,
             float* __restrict__ C2f, short* __restrict__ C2b,
             const float* __restrict__ bias2)
{
    constexpr int BM  = MI * 32;
    constexpr int MIW = MI / 2;           // fragment rows per wave
    constexpr int ASZ = BM * 32;          // shorts per A tile
    constexpr int BSZ = 128 * 32;         // shorts per B tile
    __shared__ short SA[(PREC == 3 ? 2 * D : D) * ASZ];
    __shared__ short SB[(PREC == 3 ? 2 * D : D) * BSZ];

    int bx, by;
    xcd_swz(bx, by);

    // second-descriptor selection (wave-uniform)
    const short *pAh = Ah_g, *pAl = Al_g, *pBh = Bh_g, *pBl = Bl_g;
    float* pCf = Cf_g; short* pCb = Cb_g;
    const float* pbias = bias_g; const float* pmul = mul_g;
    int pbeta = beta;
    if (A2h) {
        int yh = gridDim.y >> 1;
        if (by >= yh) {
            by -= yh;
            pAh = A2h; pAl = A2l; pBh = B2h; pBl = B2l;
            pCf = C2f; pCb = C2b; pbias = bias2; pmul = nullptr; pbeta = 0;
        }
    }

    int tid = threadIdx.x;
    int lane = tid & 63, wid = tid >> 6;   // 8 waves
    int m0 = by * BM, n0 = bx * 128;
    const short* Ab  = pAh + (size_t)m0 * lda;
    const short* Bb  = pBh + (size_t)n0 * ldb;
    const short* Abl = (PREC == 3) ? pAl + (size_t)m0 * lda : nullptr;
    const short* Bbl = (PREC == 3) ? pBl + (size_t)n0 * ldb : nullptr;

    constexpr int AISS = BM / 16;                         // 16-row issues per A tile
    constexpr int NISS = (PREC == 3) ? 2 * (AISS + 8) : (AISS + 8);
    constexpr int REM  = NISS & 7;                        // waves wid<REM issue PWH, else PWL
    constexpr int PWH  = (NISS + 7) >> 3;
    constexpr int PWL  = NISS >> 3;
    int rr = lane & 15;            // row within 16-row group
    int cc = (lane >> 4) * 8;      // k-offset (8 bf16 = 16B)

    auto stage = [&](int q, int k0) {
        short* sa  = SA + q * ASZ;
        short* sb  = SB + q * BSZ;
        short* sal = SA + (D + q) * ASZ;
        short* sbl = SB + (D + q) * BSZ;
        #pragma unroll
        for (int t = wid; t < NISS; t += 8) {
            int u = t;
            const short* g; short* l;
            if (u < AISS)              {                   g = Ab  + (size_t)(u*16+rr)*lda + k0 + cc; l = sa  + u*512; }
            else if (u < AISS + 8)     { u -= AISS;        g = Bb  + (size_t)(u*16+rr)*ldb + k0 + cc; l = sb  + u*512; }
            else if (u < 2*AISS + 8)   { u -= AISS + 8;    g = Abl + (size_t)(u*16+rr)*lda + k0 + cc; l = sal + u*512; }
            else                       { u -= 2*AISS + 8;  g = Bbl + (size_t)(u*16+rr)*ldb + k0 + cc; l = sbl + u*512; }
            gload16(g, l);
        }
    };

    f4v acc[MIW][4] = {};
    int nk = K >> 5;                       // K/32 tiles
    int P = (D - 1 < nk) ? (D - 1) : nk;   // prologue depth
    for (int q = 0; q < P; ++q) stage(q, q << 5);

    for (int kt = 0; kt < nk; ++kt) {
        int nxt = kt + D - 1;
        if (nxt < nk) stage(nxt % D, nxt << 5);
        int rem = nk - 1 - kt;
        int nf = rem < D - 1 ? rem : D - 1;
        if (REM == 0 || wid < REM) vmwait<PWH>(nf); else vmwait<PWL>(nf);
        __builtin_amdgcn_s_barrier();
        __builtin_amdgcn_sched_barrier(0);
        {
            int q = kt % D;
            int wy = wid >> 1, wx = wid & 1;
            int quad = lane >> 4, l15 = lane & 15;
            const bf8v* A8 = (const bf8v*)(SA + q * ASZ);
            const bf8v* B8 = (const bf8v*)(SB + q * BSZ);
            bf8v ah[MIW], bh[4];
            #pragma unroll
            for (int i = 0; i < MIW; i++) ah[i] = A8[(wy*MIW + i)*64 + quad*16 + l15];
            #pragma unroll
            for (int j = 0; j < 4; j++)   bh[j] = B8[(wx*4 + j)*64 + quad*16 + l15];
            if (PREC == 3) {
                const bf8v* A8l = (const bf8v*)(SA + (D + q) * ASZ);
                const bf8v* B8l = (const bf8v*)(SB + (D + q) * BSZ);
                bf8v al[MIW], bl[4];
                #pragma unroll
                for (int i = 0; i < MIW; i++) al[i] = A8l[(wy*MIW + i)*64 + quad*16 + l15];
                #pragma unroll
                for (int j = 0; j < 4; j++)   bl[j] = B8l[(wx*4 + j)*64 + quad*16 + l15];
                #pragma unroll
                for (int i = 0; i < MIW; i++)
                    #pragma unroll
                    for (int j = 0; j < 4; j++) {
                        acc[i][j] = __builtin_amdgcn_mfma_f32_16x16x32_bf16(ah[i], bh[j], acc[i][j], 0, 0, 0);
                        acc[i][j] = __builtin_amdgcn_mfma_f32_16x16x32_bf16(al[i], bh[j], acc[i][j], 0, 0, 0);
                        acc[i][j] = __builtin_amdgcn_mfma_f32_16x16x32_bf16(ah[i], bl[j], acc[i][j], 0, 0, 0);
                    }
            } else {
                #pragma unroll
                for (int i = 0; i < MIW; i++)
                    #pragma unroll
                    for (int j = 0; j < 4; j++)
                        acc[i][j] = __builtin_amdgcn_mfma_f32_16x16x32_bf16(ah[i], bh[j], acc[i][j], 0, 0, 0);
            }
        }
        __builtin_amdgcn_sched_barrier(0);
        __builtin_amdgcn_s_barrier();      // protect buf (kt % D) before next-iter stage overwrites it
        __builtin_amdgcn_sched_barrier(0);
    }

    // epilogue (C/D: col = lane&15, row = quad*4 + reg)
    int wy = wid >> 1, wx = wid & 1;
    int quad = lane >> 4, l15 = lane & 15;
    #pragma unroll
    for (int i = 0; i < MIW; i++) {
        int mb = m0 + wy * (MIW * 16) + i * 16 + quad * 4;
        #pragma unroll
        for (int j = 0; j < 4; j++) {
            int n = n0 + wx * 64 + j * 16 + l15;
            bool nin = n < Nvalid;
            #pragma unroll
            for (int r = 0; r < 4; r++) {
                int m = mb + r;
                float v = acc[i][j][r];
                if (nin) {
                    if (pbeta) v += pCf[(size_t)m * ldc + n];
                    if (pbias) v += pbias[n];
                    if (relu)  v = fmaxf(v, 0.f);
                    if (pmul)  v *= pmul[(size_t)m * ldmul + n];
                    if (pCf) pCf[(size_t)m * ldc + n] = v;
                    if (pCb) pCb[(size_t)m * ldcb + n] = f2bf(v);
                } else if (pCb && n < ldcb) {
                    pCb[(size_t)m * ldcb + n] = 0;   // zero-fill K-pad cols of bf16 outputs
                }
            }
        }
    }
}

// ---------------- fused GRU step: gh = h@whhp^T, then pointwise, in one kernel ----------
// Gate-permuted weight layout: row'(u,g) = 48*(u/16) + g*16 + (u%16), g in {r,z,n}.
// BM=64, BN=96 (= 2 gate-triple groups), 8 waves (4row x 2col), NJ=3, PREC3, D=3 (60KB).
// Each thread's 3 column-fragments are the (r,z,n) gates of ONE unit u = 16*G + l15,
// so the GRU pointwise completes in-register: no gh materialization, no second kernel.
__global__ __launch_bounds__(512)
void grugemm_k(const short* __restrict__ Ah_g, const short* __restrict__ Al_g,
               const short* __restrict__ Bh_g, const short* __restrict__ Bl_g,
               const float* __restrict__ gi, int ldgi,
               const float* __restrict__ bhhp,
               const int* __restrict__ qlen,
               float* __restrict__ h,
               short* __restrict__ qh, short* __restrict__ ql, int t)
{
    constexpr int D = 3, ASZ = 64 * 32, BSZ = 96 * 32, lda = HID, ldb = HID;
    __shared__ short SA[2 * D * ASZ];    // 24 KB
    __shared__ short SB[2 * D * BSZ];    // 36 KB

    int bx, by;
    xcd_swz(bx, by);                     // grid (32, 4), total 128

    int tid = threadIdx.x;
    int lane = tid & 63, wid = tid >> 6;
    int m0 = by * 64, n0 = bx * 96;
    const short* Ab  = Ah_g + (size_t)m0 * lda;
    const short* Bb  = Bh_g + (size_t)n0 * ldb;
    const short* Abl = Al_g + (size_t)m0 * lda;
    const short* Bbl = Bl_g + (size_t)n0 * ldb;

    constexpr int AISS = 4, BISS = 6, NISS = 2 * (AISS + BISS);   // 20
    constexpr int REM = NISS & 7, PWH = (NISS + 7) >> 3, PWL = NISS >> 3;
    int rr = lane & 15;
    int cc = (lane >> 4) * 8;

    auto stage = [&](int q, int k0) {
        short* sa  = SA + q * ASZ;
        short* sb  = SB + q * BSZ;
        short* sal = SA + (D + q) * ASZ;
        short* sbl = SB + (D + q) * BSZ;
        #pragma unroll
        for (int tt = wid; tt < NISS; tt += 8) {
            int u = tt;
            const short* g; short* l;
            if (u < AISS)                {                     g = Ab  + (size_t)(u*16+rr)*lda + k0 + cc; l = sa  + u*512; }
            else if (u < AISS + BISS)    { u -= AISS;          g = Bb  + (size_t)(u*16+rr)*ldb + k0 + cc; l = sb  + u*512; }
            else if (u < 2*AISS + BISS)  { u -= AISS + BISS;   g = Abl + (size_t)(u*16+rr)*lda + k0 + cc; l = sal + u*512; }
            else                         { u -= 2*AISS + BISS; g = Bbl + (size_t)(u*16+rr)*ldb + k0 + cc; l = sbl + u*512; }
            gload16(g, l);
        }
    };

    f4v acc[3] = {};
    constexpr int nk = HID / 32;         // 32
    for (int q = 0; q < D - 1; ++q) stage(q, q << 5);

    for (int kt = 0; kt < nk; ++kt) {
        int nxt = kt + D - 1;
        if (nxt < nk) stage(nxt % D, nxt << 5);
        int rem = nk - 1 - kt;
        int nf = rem < D - 1 ? rem : D - 1;
        if (wid < REM) vmwait<PWH>(nf); else vmwait<PWL>(nf);
        __builtin_amdgcn_s_barrier();
        __builtin_amdgcn_sched_barrier(0);
        {
            int q = kt % D;
            int wy = wid >> 1, wx = wid & 1;
            int quad = lane >> 4, l15 = lane & 15;
            const bf8v* A8  = (const bf8v*)(SA + q * ASZ);
            const bf8v* B8  = (const bf8v*)(SB + q * BSZ);
            const bf8v* A8l = (const bf8v*)(SA + (D + q) * ASZ);
            const bf8v* B8l = (const bf8v*)(SB + (D + q) * BSZ);
            bf8v ah = A8 [wy*64 + quad*16 + l15];
            bf8v al = A8l[wy*64 + quad*16 + l15];
            bf8v bh[3], bl[3];
            #pragma unroll
            for (int j = 0; j < 3; j++) { bh[j] = B8[(wx*3 + j)*64 + quad*16 + l15];
                                          bl[j] = B8l[(wx*3 + j)*64 + quad*16 + l15]; }
            #pragma unroll
            for (int j = 0; j < 3; j++) {
                acc[j] = __builtin_amdgcn_mfma_f32_16x16x32_bf16(ah, bh[j], acc[j], 0, 0, 0);
                acc[j] = __builtin_amdgcn_mfma_f32_16x16x32_bf16(al, bh[j], acc[j], 0, 0, 0);
                acc[j] = __builtin_amdgcn_mfma_f32_16x16x32_bf16(ah, bl[j], acc[j], 0, 0, 0);
            }
        }
        __builtin_amdgcn_sched_barrier(0);
        __builtin_amdgcn_s_barrier();
        __builtin_amdgcn_sched_barrier(0);
    }

    // fused GRU epilogue
    int wy = wid >> 1, wx = wid & 1;
    int quad = lane >> 4, l15 = lane & 15;
    int mb = m0 + wy * 16 + quad * 4;
    int n0w = n0 + wx * 48;
    int u = (n0w / 48) * 16 + l15;       // unit index in [0, 1024)
    float br = bhhp[n0w + l15], bz = bhhp[n0w + 16 + l15], bn = bhhp[n0w + 32 + l15];
    #pragma unroll
    for (int r = 0; r < 4; r++) {
        int m = mb + r;
        const float* gim = gi + (size_t)m * ldgi + n0w;
        float ir = gim[l15], iz = gim[16 + l15], in = gim[32 + l15];
        float hr = acc[0][r] + br, hz = acc[1][r] + bz, hn = acc[2][r] + bn;
        float rg = 1.f / (1.f + expf(-(ir + hr)));
        float z  = 1.f / (1.f + expf(-(iz + hz)));
        float nn = tanhf(in + rg * hn);
        size_t hi_ = (size_t)m * HID + u;
        float hold = h[hi_];
        float val = (t < qlen[m]) ? ((1.f - z) * nn + z * hold) : hold;
        h[hi_] = val;
        short hh = f2bf(val);
        qh[hi_] = hh;
        ql[hi_] = f2bf(val - bf2f(hh));
    }
}

static void mgx(hipStream_t s, int prec, int mi,
                const short* Ah, const short* Al, int lda,
                const short* Bh, const short* Bl, int ldb,
                float* Cf, int ldc, short* Cb, int ldcb,
                const float* bias, const float* mul, int ldmul,
                int M, int N, int K, int beta, int relu,
                int ydup,
                const short* A2h, const short* A2l,
                const short* B2h, const short* B2l,
                float* C2f, short* C2b, const float* bias2)
{
    dim3 grid((N + 127) / 128, (M / (mi * 32)) * ydup);
    #define ARGS Ah,Al,lda,Bh,Bl,ldb,Cf,ldc,Cb,ldcb,bias,mul,ldmul,N,K,beta,relu,A2h,A2l,B2h,B2l,C2f,C2b,bias2
    if (prec == 3) {
        if (mi == 4) mgemm_k<3,4,2><<<grid,512,0,s>>>(ARGS);   // 64 KB -> 2 blk/CU
        else         mgemm_k<3,2,3><<<grid,512,0,s>>>(ARGS);   // 72 KB
    } else {
        if (mi == 4) mgemm_k<1,4,4><<<grid,512,0,s>>>(ARGS);   // 48 KB -> 3 blk/CU
        else         mgemm_k<1,2,4><<<grid,512,0,s>>>(ARGS);   // 40 KB
    }
    #undef ARGS
}

static void mg(hipStream_t s, int prec, int mi,
               const short* Ah, const short* Al, int lda,
               const short* Bh, const short* Bl, int ldb,
               float* Cf, int ldc, short* Cb, int ldcb,
               const float* bias, const float* mul, int ldmul,
               int M, int N, int K, int beta, int relu)
{
    mgx(s, prec, mi, Ah, Al, lda, Bh, Bl, ldb, Cf, ldc, Cb, ldcb, bias, mul, ldmul,
        M, N, K, beta, relu, 1, nullptr, nullptr, nullptr, nullptr, nullptr, nullptr, nullptr);
}

// ---------------- conversion / small kernels ----------------
__global__ void fill0_k(float* p, int n) {
    int i = blockIdx.x * 256 + threadIdx.x;
    if (i < n) p[i] = 0.f;
}

// fp32 (srows,scols,sld) -> bf16 hi[,lo] (.., dld) zero-padded.
// gperm: dst row r' maps to src row gate*1024+u (GRU gate-triple permutation).
__global__ void cvt_k(const float* __restrict__ src, int sld, int srows, int scols,
                      short* __restrict__ hi, short* __restrict__ lo, int dld, int n,
                      int gperm) {
    int i = blockIdx.x * 256 + threadIdx.x;
    if (i >= n) return;
    int r = i / dld, c = i - r * dld;
    int sr = r;
    if (gperm) {
        int G = r / 48, rem = r - G * 48;
        int gate = rem >> 4, l = rem & 15;
        sr = gate * 1024 + 16 * G + l;
    }
    float v = (sr < srows && c < scols) ? src[(size_t)sr * sld + c] : 0.f;
    short h = f2bf(v);
    hi[i] = h;
    if (lo) lo[i] = f2bf(v - bf2f(h));
}

// permute a 3072-vector into gate-triple layout (fp32)
__global__ void permb_k(const float* __restrict__ src, float* __restrict__ dst) {
    int r = blockIdx.x * 256 + threadIdx.x;
    if (r >= 3 * HID) return;
    int G = r / 48, rem = r - G * 48;
    int gate = rem >> 4, l = rem & 15;
    dst[r] = src[gate * 1024 + 16 * G + l];
}

__global__ void embed_k(const int* __restrict__ q, const float* __restrict__ wemb,
                        short* __restrict__ hi, short* __restrict__ lo) {
    int i = blockIdx.x * 256 + threadIdx.x;
    if (i >= BATCH * QLEN_ * 320) return;
    int c = i % 320; int bt = i / 320;
    float v = (c < EMB) ? wemb[(size_t)q[bt] * EMB + c] : 0.f;
    short h = f2bf(v);
    hi[i] = h;
    lo[i] = f2bf(v - bf2f(h));
}

__global__ __launch_bounds__(256)
void attraw_k(const float* __restrict__ proj, const float* __restrict__ qproj,
              const float* __restrict__ attw, const float* __restrict__ attb,
              float* __restrict__ raw, int L) {
    int wave = blockIdx.x * 4 + (threadIdx.x >> 6);
    int lane = threadIdx.x & 63;
    if (wave >= BATCH * L) return;
    int b = wave / L;
    const float* p = proj + (size_t)wave * HID;
    const float* q = qproj + (size_t)b * HID;
    float s = 0.f;
    for (int hh = lane; hh < HID; hh += 64) s += p[hh] * q[hh] * attw[hh];
    #pragma unroll
    for (int o = 32; o; o >>= 1) s += __shfl_down(s, o, 64);
    if (lane == 0) raw[wave] = s + attb[0];
}

__global__ void softmax_k(float* raw, int L) {
    int b = blockIdx.x * blockDim.x + threadIdx.x;
    if (b >= BATCH) return;
    float* r = raw + (size_t)b * L;
    float mx = -1e30f;
    for (int l = 0; l < L; l++) mx = fmaxf(mx, r[l]);
    float sum = 0.f;
    for (int l = 0; l < L; l++) { float e = expf(r[l] - mx); r[l] = e; sum += e; }
    float inv = 1.f / sum;
    for (int l = 0; l < L; l++) r[l] *= inv;
}

// bf16-out weighted sum with K-pad: out[b, c<dld] = sum_l src[(b*L+l)*sF + c] * att[b*L+l]
__global__ void wsumb_k(const float* __restrict__ src, int sF, const float* __restrict__ att,
                        int L, short* __restrict__ outh, int dld, int n) {
    int i = blockIdx.x * 256 + threadIdx.x;
    if (i >= n) return;
    int c = i % dld; int b = i / dld;
    float s = 0.f;
    if (c < sF)
        for (int l = 0; l < L; l++) s += src[((size_t)b * L + l) * sF + c] * att[b * L + l];
    outh[i] = f2bf(s);
}

// jax.lax.top_k: descending, ties -> lowest index
__global__ void topk_k(const float* __restrict__ att, int* __restrict__ idx) {
    int b = blockIdx.x * blockDim.x + threadIdx.x;
    if (b >= BATCH) return;
    float v[KOBJ]; bool taken[KOBJ];
    for (int l = 0; l < KOBJ; l++) { v[l] = att[(size_t)b * KOBJ + l]; taken[l] = false; }
    for (int s = 0; s < NS; s++) {
        float best = -1e30f; int bi = 0;
        for (int l = 0; l < KOBJ; l++)
            if (!taken[l] && v[l] > best) { best = v[l]; bi = l; }
        taken[bi] = true;
        idx[b * NS + s] = bi;
    }
}

// gather top-k rows: fp32 (ld 2052) + bf16 hi (ld 2080, zero pad)
__global__ void gather_k(const float* __restrict__ img, const int* __restrict__ idx,
                         float* __restrict__ outf, short* __restrict__ outh) {
    int i = blockIdx.x * 256 + threadIdx.x;
    if (i >= BATCH * NS * 2080) return;
    int c = i % 2080; int bs = i / 2080; int b = bs / NS; int s = bs % NS;
    float v = 0.f;
    if (c < FEAT) {
        v = img[((size_t)b * KOBJ + idx[b * NS + s]) * FEAT + c];
        outf[(size_t)bs * FEAT + c] = v;
    }
    outh[i] = f2bf(v);
}

__global__ void kw_k(const float* __restrict__ image, const int* __restrict__ tidx,
                     const float* __restrict__ mu1, const float* __restrict__ sig1,
                     const float* __restrict__ mu2, const float* __restrict__ sig2,
                     float* __restrict__ kw1, float* __restrict__ kw2) {
    int i = blockIdx.x * blockDim.x + threadIdx.x;
    if (i >= BATCH * NS * NS) return;
    int m = i % NS; int bn = i / NS; int b = bn / NS; int n = bn % NS;
    const float* bbn = image + ((size_t)b * KOBJ + tidx[b * NS + n]) * FEAT + (FEAT - 4);
    const float* bbm = image + ((size_t)b * KOBJ + tidx[b * NS + m]) * FEAT + (FEAT - 4);
    float cnx = bbn[0] + 0.5f * (bbn[2] - bbn[0]);
    float cny = bbn[1] + 0.5f * (bbn[3] - bbn[1]);
    float cmx = bbm[0] + 0.5f * (bbm[2] - bbm[0]);
    float cmy = bbm[1] + 0.5f * (bbm[3] - bbm[1]);
    float d0 = cnx - cmx, d1 = cny - cmy;
    float rho = sqrtf(d0 * d0 + d1 * d1);
    float theta = atan2f(d0, d1);
    #pragma unroll
    for (int k = 0; k < NK; k++) {
        float a1 = (rho   - mu1[k * 2 + 0]) / (1e-14f + sig1[k * 2 + 0]);
        float b1 = (theta - mu1[k * 2 + 1]) / (1e-14f + sig1[k * 2 + 1]);
        kw1[(size_t)i * NK + k] = expf(-0.5f * (a1 * a1 + b1 * b1));
        float a2 = (rho   - mu2[k * 2 + 0]) / (1e-14f + sig2[k * 2 + 0]);
        float b2 = (theta - mu2[k * 2 + 1]) / (1e-14f + sig2[k * 2 + 1]);
        kw2[(size_t)i * NK + k] = expf(-0.5f * (a2 * a2 + b2 * b2));
    }
}

// graph-conv mix, kw cached in LDS, Y read exactly once.
__global__ __launch_bounds__(256)
void mixn_k(const float* __restrict__ Y, const float* __restrict__ kw,
            const float* __restrict__ bias, short* __restrict__ outh,
            float* __restrict__ outf, int KO, int CT) {
    __shared__ float kws[NS * NS * NK];   // 800
    int b = blockIdx.y;
    for (int i = threadIdx.x; i < NS * NS * NK; i += 256)
        kws[i] = kw[(size_t)b * (NS * NS * NK) + i];
    __syncthreads();
    int c = blockIdx.x * 256 + threadIdx.x;
    int k = c / KO;
    const float* Yp = Y + ((size_t)b * NS) * CT + c;
    float acc[NS];
    #pragma unroll
    for (int n = 0; n < NS; n++) acc[n] = 0.f;
    #pragma unroll
    for (int m = 0; m < NS; m++) {
        float y = Yp[(size_t)m * CT];
        #pragma unroll
        for (int n = 0; n < NS; n++) acc[n] += kws[n * (NS * NK) + m * NK + k] * y;
    }
    float bc = bias[c];
    #pragma unroll
    for (int n = 0; n < NS; n++) {
        float s = fmaxf(acc[n] + bc, 0.f);
        size_t o = ((size_t)b * NS + n) * CT + c;
        outh[o] = f2bf(s);
        if (outf) outf[o] = s;
    }
}

// out[i] = t1[i] + t2[i]
__global__ void addout_k(const float* __restrict__ t1, const float* __restrict__ t2,
                         float* __restrict__ out, int n) {
    int i = blockIdx.x * 256 + threadIdx.x;
    if (i < n) out[i] = t1[i] + t2[i];
}

// transpose+convert per k-slice: dst[k*O+o][f<dld] = src[k][f][o] (zero-pad f>=S)
__global__ void packcvt_k(const float* __restrict__ src, short* __restrict__ dst,
                          int S, int O, int dld) {
    __shared__ float t[32][33];
    int k = blockIdx.z;
    const float* s = src + (size_t)k * S * O;
    short* d = dst + (size_t)k * O * dld;
    int f0 = blockIdx.y * 32, o0 = blockIdx.x * 32;
    for (int i = threadIdx.y; i < 32; i += 8) {
        int f = f0 + i, o = o0 + threadIdx.x;
        t[i][threadIdx.x] = (f < S && o < O) ? s[(size_t)f * O + o] : 0.f;
    }
    __syncthreads();
    for (int i = threadIdx.y; i < 32; i += 8) {
        int o = o0 + i, f = f0 + threadIdx.x;
        if (o < O && f < dld) d[(size_t)o * dld + f] = f2bf(t[threadIdx.x][i]);
    }
}

// ---------------- launch ----------------
extern "C" void kernel_launch(void* const* d_in, const int* in_sizes, int n_in,
                              void* d_out, int out_size, void* d_ws, size_t ws_size,
                              hipStream_t stream)
{
    const int*   question  = (const int*)d_in[0];
    const float* image     = (const float*)d_in[1];
    const int*   qlen      = (const int*)d_in[3];
    const float* wembed    = (const float*)d_in[4];
    const float* gru_wih   = (const float*)d_in[5];
    const float* gru_whh   = (const float*)d_in[6];
    const float* gru_bih   = (const float*)d_in[7];
    const float* gru_bhh   = (const float*)d_in[8];
    const float* ia_img_w  = (const float*)d_in[9];
    const float* ia_img_b  = (const float*)d_in[10];
    const float* ia_txt_w  = (const float*)d_in[11];
    const float* ia_txt_b  = (const float*)d_in[12];
    const float* ia_att_w  = (const float*)d_in[13];
    const float* ia_att_b  = (const float*)d_in[14];
    const float* ga_img_w  = (const float*)d_in[15];
    const float* ga_img_b  = (const float*)d_in[16];
    const float* ga_txt_w  = (const float*)d_in[17];
    const float* ga_txt_b  = (const float*)d_in[18];
    const float* ga_att_w  = (const float*)d_in[19];
    const float* ga_att_b  = (const float*)d_in[20];
    const float* gc1_mu    = (const float*)d_in[21];
    const float* gc1_sigma = (const float*)d_in[22];
    const float* gc1_w     = (const float*)d_in[23];
    const float* gc1_b     = (const float*)d_in[24];
    const float* gc2_mu    = (const float*)d_in[25];
    const float* gc2_sigma = (const float*)d_in[26];
    const float* gc2_w     = (const float*)d_in[27];
    const float* gc2_b     = (const float*)d_in[28];
    const float* out1_w    = (const float*)d_in[29];
    const float* out1_b    = (const float*)d_in[30];
    const float* out2_w    = (const float*)d_in[31];
    const float* out2_b    = (const float*)d_in[32];
    const float* iout1_w   = (const float*)d_in[33];
    const float* iout1_b   = (const float*)d_in[34];
    const float* iout2_w   = (const float*)d_in[35];
    const float* iout2_b   = (const float*)d_in[36];
    float* out = (float*)d_out;

    float* ws = (float*)d_ws;
    size_t off = 0;
    auto alloc  = [&](size_t n)   { size_t o = off; off += (n + 63) & ~(size_t)63; return ws + o; };
    auto allocS = [&](size_t nsh) { return (short*)alloc((nsh + 1) >> 1); };

    // persistent fp32
    float* qenc   = alloc((size_t)BATCH * HID);
    float* att_ia = alloc((size_t)BATCH * KOBJ);
    float* att_ga = alloc((size_t)BATCH * NS);
    int*   tidx   = (int*)alloc((size_t)BATCH * NS);
    float* timg_f = alloc((size_t)2560 * FEAT);
    float* kw1    = alloc((size_t)BATCH * NS * NS * NK);
    float* kw2    = alloc((size_t)BATCH * NS * NS * NK);
    float* bihp   = alloc(3 * HID);
    float* bhhp   = alloc(3 * HID);
    // persistent bf16 (hi/lo pairs for PREC3 scoring path; wih/whh gate-permuted)
    short* wih_h   = allocS((size_t)3072 * 320);  short* wih_l   = allocS((size_t)3072 * 320);
    short* whh_h   = allocS((size_t)3072 * 1024); short* whh_l   = allocS((size_t)3072 * 1024);
    short* iaimg_h = allocS((size_t)1024 * 2080); short* iaimg_l = allocS((size_t)1024 * 2080);
    short* iatxt_h = allocS((size_t)1024 * 1024); short* iatxt_l = allocS((size_t)1024 * 1024);
    short* emb_h   = allocS((size_t)3584 * 320);  short* emb_l   = allocS((size_t)3584 * 320);
    short* qenc_h  = allocS((size_t)256 * 1024);  short* qenc_l  = allocS((size_t)256 * 1024);
    // phase-reused regions
    float* R1 = alloc(12600000);   // 25.2M shorts
    float* U  = alloc(19200000);   // 38.4M shorts

    // --- phase-local views ---
    // A: GRU
    float* gi_all = R1;                          // 3584 x 3072 (gate-permuted cols)
    // B: image attention
    float* improj = R1;                          // 9216 x 1024
    float* qproj  = R1 + 9437184;                // 256 x 1024
    short* img_h  = (short*)U;                   // 9216 x 2080
    short* img_l  = (short*)U + 19169280;
    short* imatt_h = (short*)U + 13189120;       // 256 x 2080 (after img dead)
    // C: graph convs
    float* Y1 = R1;                              // 2560 x 2048
    float* Y2 = R1 + 5242880;                    // 2560 x 1024
    short* gc1t_h = (short*)(R1 + 7864320);      // 2048 x 2080
    short* gc2t_h = (short*)(R1 + 7864320) + 4259840; // 1024 x 2048
    short* timg_h = (short*)U;                   // 2560 x 2080
    short* h1_h   = (short*)U + 5324800;         // 2560 x 2048
    short* h2_h   = (short*)U + 10567680;        // 2560 x 1024
    float* h2_f   = (float*)((short*)U + 20807680); // 2560 x 1024 fp32
    // D: graph attention
    float* gproj   = R1;                         // 2560 x 1024
    float* qproj2  = R1 + 2621440;               // 256 x 1024
    float* gtmp    = R1 + 2883584;               // 256 x 1024
    short* gatt_img_h = (short*)U + 13721600;    // 256 x 2080
    short* gatt_h2_h  = (short*)U + 14254080;    // 256 x 1024
    short* gcomb_h = (short*)U + 14516224;       // 256 x 1024
    short* icomb_h = (short*)U + 14778368;       // 256 x 1024
    short* hid1_h  = (short*)U + 15040512;       // 256 x 3008
    short* hid2_h  = (short*)U + 15810560;       // 256 x 3008
    short* gaw_img_h = (short*)U + 16580608;     // 1024 x 2080
    short* gaw_h2_h  = (short*)U + 18710528;     // 1024 x 1024
    short* gatxt_h   = (short*)U + 19759104;     // 1024 x 1024
    float* tmp1 = (float*)((short*)U + 26050560); // 256 x 3000 fp32
    float* tmp2 = tmp1 + 768000;                  // 256 x 3000 fp32
    // E: output weights (into R1, after gcomb done)
    short* o1w_h  = (short*)R1;                  // 3072 x 1024
    short* io1w_h = (short*)R1 + 3145728;
    short* o2w_h  = (short*)R1 + 6291456;        // 3072 x 3008
    short* io2w_h = (short*)R1 + 15532032;

    auto NB = [](size_t n) { return (unsigned)((n + 255) / 256); };

    // ===== conversions (phase A/B weights + image; wih/whh gate-permuted) =====
    cvt_k<<<NB(983040),  256, 0, stream>>>(gru_wih, 300, 3072, 300, wih_h, wih_l, 320, 983040, 1);
    cvt_k<<<NB(3145728), 256, 0, stream>>>(gru_whh, 1024, 3072, 1024, whh_h, whh_l, 1024, 3145728, 1);
    permb_k<<<NB(3072), 256, 0, stream>>>(gru_bih, bihp);
    permb_k<<<NB(3072), 256, 0, stream>>>(gru_bhh, bhhp);
    cvt_k<<<NB(2129920), 256, 0, stream>>>(ia_img_w, FEAT, 1024, FEAT, iaimg_h, iaimg_l, 2080, 2129920, 0);
    cvt_k<<<NB(1048576), 256, 0, stream>>>(ia_txt_w, 1024, 1024, 1024, iatxt_h, iatxt_l, 1024, 1048576, 0);
    cvt_k<<<NB(19169280),256, 0, stream>>>(image, FEAT, 9216, FEAT, img_h, img_l, 2080, 19169280, 0);
    embed_k<<<NB(1146880), 256, 0, stream>>>(question, wembed, emb_h, emb_l);
    fill0_k<<<NB(262144), 256, 0, stream>>>(qenc, 262144);
    fill0_k<<<NB(262144), 256, 0, stream>>>((float*)qenc_h, 262144);   // zeros qenc_h + qenc_l

    // ===== Phase A: GRU (gi precompute, then 14 fused GEMM+pointwise steps) =====
    mg(stream, 3, 4, emb_h, emb_l, 320, wih_h, wih_l, 320, gi_all, 3072, nullptr, 0,
       bihp, nullptr, 0, 3584, 3072, 320, 0, 0);
    for (int t = 0; t < QLEN_; t++) {
        grugemm_k<<<dim3(32, 4), 512, 0, stream>>>(qenc_h, qenc_l, whh_h, whh_l,
                                                   gi_all + (size_t)t * 3 * HID, QLEN_ * 3 * HID,
                                                   bhhp, qlen, qenc, qenc_h, qenc_l, t);
    }

    // ===== Phase B: image attention (scoring = PREC3) =====
    mg(stream, 3, 4, img_h, img_l, 2080, iaimg_h, iaimg_l, 2080, improj, 1024, nullptr, 0,
       ia_img_b, nullptr, 0, 9216, 1024, 2080, 0, 1);
    mg(stream, 3, 2, qenc_h, qenc_l, 1024, iatxt_h, iatxt_l, 1024, qproj, 1024, nullptr, 0,
       ia_txt_b, nullptr, 0, 256, 1024, 1024, 0, 1);
    attraw_k<<<(BATCH * KOBJ) / 4, 256, 0, stream>>>(improj, qproj, ia_att_w, ia_att_b, att_ia, KOBJ);
    softmax_k<<<1, 256, 0, stream>>>(att_ia, KOBJ);
    wsumb_k<<<NB(532480), 256, 0, stream>>>(image, FEAT, att_ia, KOBJ, imatt_h, 2080, 532480);
    mg(stream, 1, 2, imatt_h, nullptr, 2080, iaimg_h, nullptr, 2080, nullptr, 0, icomb_h, 1024,
       ia_img_b, qproj, 1024, 256, 1024, 2080, 0, 1);

    // ===== Phase C: top-k + graph convs =====
    topk_k<<<1, 256, 0, stream>>>(att_ia, tidx);
    gather_k<<<NB(5324800), 256, 0, stream>>>(image, tidx, timg_f, timg_h);
    kw_k<<<NB(25600), 256, 0, stream>>>(image, tidx, gc1_mu, gc1_sigma, gc2_mu, gc2_sigma, kw1, kw2);
    packcvt_k<<<dim3(8, 65, NK), dim3(32, 8), 0, stream>>>(gc1_w, gc1t_h, FEAT, 256, 2080);
    packcvt_k<<<dim3(4, 64, NK), dim3(32, 8), 0, stream>>>(gc2_w, gc2t_h, 2048, 128, 2048);
    mg(stream, 1, 4, timg_h, nullptr, 2080, gc1t_h, nullptr, 2080, Y1, 2048, nullptr, 0,
       nullptr, nullptr, 0, 2560, 2048, 2080, 0, 0);
    mixn_k<<<dim3(8, BATCH), 256, 0, stream>>>(Y1, kw1, gc1_b, h1_h, nullptr, 256, 2048);
    mg(stream, 1, 4, h1_h, nullptr, 2048, gc2t_h, nullptr, 2048, Y2, 1024, nullptr, 0,
       nullptr, nullptr, 0, 2560, 1024, 2048, 0, 0);
    mixn_k<<<dim3(4, BATCH), 256, 0, stream>>>(Y2, kw2, gc2_b, h2_h, h2_f, 128, 1024);

    // ===== Phase D: graph attention ([timg | h2], never materialized) =====
    cvt_k<<<NB(2129920), 256, 0, stream>>>(ga_img_w, FEAT + HID, 1024, FEAT, gaw_img_h, nullptr, 2080, 2129920, 0);
    cvt_k<<<NB(1048576), 256, 0, stream>>>(ga_img_w + FEAT, FEAT + HID, 1024, HID, gaw_h2_h, nullptr, 1024, 1048576, 0);
    cvt_k<<<NB(1048576), 256, 0, stream>>>(ga_txt_w, 1024, 1024, 1024, gatxt_h, nullptr, 1024, 1048576, 0);
    mg(stream, 1, 4, timg_h, nullptr, 2080, gaw_img_h, nullptr, 2080, gproj, 1024, nullptr, 0,
       nullptr, nullptr, 0, 2560, 1024, 2080, 0, 0);
    mg(stream, 1, 4, h2_h, nullptr, 1024, gaw_h2_h, nullptr, 1024, gproj, 1024, nullptr, 0,
       ga_img_b, nullptr, 0, 2560, 1024, 1024, 1, 1);
    mg(stream, 1, 2, qenc_h, nullptr, 1024, gatxt_h, nullptr, 1024, qproj2, 1024, nullptr, 0,
       ga_txt_b, nullptr, 0, 256, 1024, 1024, 0, 1);
    attraw_k<<<(BATCH * NS) / 4, 256, 0, stream>>>(gproj, qproj2, ga_att_w, ga_att_b, att_ga, NS);
    softmax_k<<<1, 256, 0, stream>>>(att_ga, NS);
    wsumb_k<<<NB(532480), 256, 0, stream>>>(timg_f, FEAT, att_ga, NS, gatt_img_h, 2080, 532480);
    wsumb_k<<<NB(262144), 256, 0, stream>>>(h2_f, HID, att_ga, NS, gatt_h2_h, 1024, 262144);
    mg(stream, 1, 2, gatt_img_h, nullptr, 2080, gaw_img_h, nullptr, 2080, gtmp, 1024, nullptr, 0,
       nullptr, nullptr, 0, 256, 1024, 2080, 0, 0);
    mg(stream, 1, 2, gatt_h2_h, nullptr, 1024, gaw_h2_h, nullptr, 1024, gtmp, 1024, gcomb_h, 1024,
       ga_img_b, qproj2, 1024, 256, 1024, 1024, 1, 1);

    // ===== Phase E: output MLPs (pairs merged into single dispatches) =====
    cvt_k<<<NB(3145728), 256, 0, stream>>>(out1_w, 1024, OUTN, 1024, o1w_h, nullptr, 1024, 3145728, 0);
    cvt_k<<<NB(3145728), 256, 0, stream>>>(iout1_w, 1024, OUTN, 1024, io1w_h, nullptr, 1024, 3145728, 0);
    cvt_k<<<NB(9240576), 256, 0, stream>>>(out2_w, OUTN, OUTN, OUTN, o2w_h, nullptr, 3008, 9240576, 0);
    cvt_k<<<NB(9240576), 256, 0, stream>>>(iout2_w, OUTN, OUTN, OUTN, io2w_h, nullptr, 3008, 9240576, 0);
    // hid1 = relu(gcomb@o1w^T + b) ; hid2 = relu(icomb@io1w^T + b)  -- one dispatch
    mgx(stream, 1, 2, gcomb_h, nullptr, 1024, o1w_h, nullptr, 1024, nullptr, 0, hid1_h, 3008,
        out1_b, nullptr, 0, 256, OUTN, 1024, 0, 1,
        2, icomb_h, nullptr, io1w_h, nullptr, nullptr, hid2_h, iout1_b);
    // tmp1 = hid1@o2w^T + b2 ; tmp2 = hid2@io2w^T + ib2  -- one dispatch, then sum
    mgx(stream, 1, 2, hid1_h, nullptr, 3008, o2w_h, nullptr, 3008, tmp1, 3000, nullptr, 0,
        out2_b, nullptr, 0, 256, OUTN, 3008, 0, 0,
        2, hid2_h, nullptr, io2w_h, nullptr, tmp2, nullptr, iout2_b);
    addout_k<<<NB(768000), 256, 0, stream>>>(tmp1, tmp2, out, 768000);
}